// Round 8
// baseline (82.076 us; speedup 1.0000x reference)
//
#include <hip/hip_runtime.h>

typedef __attribute__((ext_vector_type(8))) short short8_t;      // 8 bf16
typedef __attribute__((ext_vector_type(4))) float float4_t;      // MFMA C/D frag

#define MFMA __builtin_amdgcn_mfma_f32_16x16x32_bf16
#define VMCNT(n) asm volatile("s_waitcnt vmcnt(" #n ")" ::: "memory")
#define LGKM0    asm volatile("s_waitcnt lgkmcnt(0)" ::: "memory")
#define BARRIER  __builtin_amdgcn_s_barrier()

constexpr int BB   = 4;
constexpr int LL   = 2048;
constexpr int DM   = 1024;
constexpr int DK   = 128;
constexpr int MTOT = BB * LL;     // 8192
constexpr int MC   = 4;
constexpr float INV2PI = 0.15915494309189535f;

__device__ __forceinline__ unsigned short f2bf(float f) {
    unsigned int u = __builtin_bit_cast(unsigned int, f);
    u += 0x7FFFu + ((u >> 16) & 1u);          // RNE
    return (unsigned short)(u >> 16);
}
__device__ __forceinline__ float bf2f(unsigned short h) {
    unsigned int u = ((unsigned int)h) << 16;
    return __builtin_bit_cast(float, u);
}
__device__ __forceinline__ void gload16(const void* g, void* l) {
    __builtin_amdgcn_global_load_lds(
        (const __attribute__((address_space(1))) void*)g,
        (__attribute__((address_space(3))) void*)l, 16, 0, 0);
}

// ---------------------------------------------------------------------------
// K0: W [1024 k][128 n] f32 -> fragment-major W^T images, hi/lo bf16.
// Image: [kc 32][cbt 8][g 4][cc 16][e 8]; element (n,k): kc=k>>5, g=(k>>3)&3,
// e=k&7, cbt=n>>4, cc=n&15.  grid (32 kc, 3 arr), block 256.
// ---------------------------------------------------------------------------
__global__ __launch_bounds__(256) void k0_wsplit(
        const float* __restrict__ wq, const float* __restrict__ wk,
        const float* __restrict__ wv,
        unsigned short* __restrict__ wqh, unsigned short* __restrict__ wql,
        unsigned short* __restrict__ wkh, unsigned short* __restrict__ wkl,
        unsigned short* __restrict__ wvh) {
    int kc = blockIdx.x, a = blockIdx.y;
    const float* w = (a == 0) ? wq : (a == 1) ? wk : wv;
    __shared__ float tile[32 * 132];          // [k 32][n 128] pad->132
    int t = threadIdx.x;
#pragma unroll
    for (int j = 0; j < 4; ++j) {
        int idx4 = t + j * 256;               // 1024 float4s
        int kr = idx4 >> 5, n4 = idx4 & 31;
        *(float4_t*)(&tile[kr * 132 + n4 * 4]) =
            *(const float4_t*)(w + (size_t)(kc * 32 + kr) * DK + n4 * 4);
    }
    __syncthreads();
#pragma unroll
    for (int sw = 0; sw < 2; ++sw) {
        int ch = t + sw * 256;                // 512 16B-chunks: (cbt*4+g)*16+cc
        int cbt = ch >> 6, g = (ch >> 4) & 3, cc = ch & 15;
        short8_t hh, ll;
#pragma unroll
        for (int e = 0; e < 8; ++e) {
            float f = tile[(g * 8 + e) * 132 + cbt * 16 + cc];
            unsigned short h = f2bf(f);
            hh[e] = (short)h;
            ll[e] = (short)f2bf(f - bf2f(h));
        }
        size_t off = (size_t)kc * 4096 + ch * 8;
        if (a == 0) { *(short8_t*)(wqh + off) = hh; *(short8_t*)(wql + off) = ll; }
        else if (a == 1) { *(short8_t*)(wkh + off) = hh; *(short8_t*)(wkl + off) = ll; }
        else { *(short8_t*)(wvh + off) = hh; }
    }
}

// ---------------------------------------------------------------------------
// K1 v6: QKV projection. BM=64, BK=32; grid (128 mt, 3 grp); 4 waves, wave
// tile 32x64. Ring-3 LDS, prefetch distance 2 for W (gload_lds) and x
// (global->reg->swizzled ds_write f32; bf16 convert in-register in compute).
// Exact vmcnt ledger; 2 raw barriers/step, no drains.
// ---------------------------------------------------------------------------
__global__ __launch_bounds__(256, 2) void k1_proj(
        const float* __restrict__ x,
        const float* __restrict__ bq, const float* __restrict__ bk,
        const float* __restrict__ bv,
        const unsigned short* __restrict__ wqh, const unsigned short* __restrict__ wql,
        const unsigned short* __restrict__ wkh, const unsigned short* __restrict__ wkl,
        const unsigned short* __restrict__ wvh,
        unsigned short* __restrict__ qih, unsigned short* __restrict__ qil,
        unsigned short* __restrict__ kih, unsigned short* __restrict__ kil,
        unsigned short* __restrict__ vit) {
    int mt = blockIdx.x, grp = blockIdx.y;
    int rowbase = mt * 64;
    __shared__ __attribute__((aligned(16))) unsigned short wbh[3][4096]; // 8KB ea
    __shared__ __attribute__((aligned(16))) unsigned short wbl[3][4096];
    __shared__ __attribute__((aligned(16))) float xb[3][2048];           // 8KB ea

    int t = threadIdx.x, lane = t & 63, wid = t >> 6;
    int cc = lane & 15, g = lane >> 4;
    int wr = wid >> 1, wc = wid & 1;          // wave tile rows wr*32, cols wc*64
    const bool split = (grp < 2);
    const unsigned short* Wh = (grp == 0) ? wqh : (grp == 1) ? wkh : wvh;
    const unsigned short* Wl = (grp == 0) ? wql : wkl;

    float4_t acc[2][4];
#pragma unroll
    for (int rf = 0; rf < 2; ++rf)
#pragma unroll
        for (int cf = 0; cf < 4; ++cf) acc[rf][cf] = (float4_t){0.f, 0.f, 0.f, 0.f};

    // x staging map: thread -> row r=t>>2, 8-f32 chunk c8=t&3; swizzled 16B slots
    int xr_ = t >> 2, xc8 = t & 3;
    const float* xsrc = x + (size_t)(rowbase + xr_) * DM + xc8 * 8;
    int xw0 = xr_ * 32 + (((xc8 * 2)     ^ (xr_ & 7)) << 2);   // f32 units
    int xw1 = xr_ * 32 + (((xc8 * 2 + 1) ^ (xr_ & 7)) << 2);

    auto stageW = [&](int kc, int buf) {
        const unsigned short* Whp = Wh + (size_t)kc * 4096;
        gload16(Whp + t * 8, (char*)wbh[buf] + wid * 1024);
        gload16(Whp + 2048 + t * 8, (char*)wbh[buf] + 4096 + wid * 1024);
        if (split) {
            const unsigned short* Wlp = Wl + (size_t)kc * 4096;
            gload16(Wlp + t * 8, (char*)wbl[buf] + wid * 1024);
            gload16(Wlp + 2048 + t * 8, (char*)wbl[buf] + 4096 + wid * 1024);
        }
    };
    auto compute = [&](int cur) {
        short8_t ah[2], al[2];
#pragma unroll
        for (int rf = 0; rf < 2; ++rf) {
            int row = wr * 32 + rf * 16 + cc;
            const float* xrow = &xb[cur][row * 32];
            float4_t f0 = *(const float4_t*)(xrow + (((2 * g)     ^ (row & 7)) << 2));
            float4_t f1 = *(const float4_t*)(xrow + (((2 * g + 1) ^ (row & 7)) << 2));
#pragma unroll
            for (int e = 0; e < 8; ++e) {
                float f = (e < 4) ? f0[e] : f1[e - 4];
                unsigned short h = f2bf(f);
                ah[rf][e] = (short)h;
                if (split) al[rf][e] = (short)f2bf(f - bf2f(h));
            }
        }
#pragma unroll
        for (int cf = 0; cf < 4; ++cf) {
            int cbt = wc * 4 + cf;
            short8_t bh = *(const short8_t*)(&wbh[cur][cbt * 512 + lane * 8]);
            short8_t bl;
            if (split) bl = *(const short8_t*)(&wbl[cur][cbt * 512 + lane * 8]);
#pragma unroll
            for (int rf = 0; rf < 2; ++rf) {
                acc[rf][cf] = MFMA(ah[rf], bh, acc[rf][cf], 0, 0, 0);
                if (split) {
                    acc[rf][cf] = MFMA(ah[rf], bl, acc[rf][cf], 0, 0, 0);
                    acc[rf][cf] = MFMA(al[rf], bh, acc[rf][cf], 0, 0, 0);
                }
            }
        }
    };

    // ---- prologue: x(0) via xE, x(1) via xO; W(0),W(1)
    float4_t xE0, xE1, xO0, xO1;
    xE0 = *(const float4_t*)(xsrc);
    xE1 = *(const float4_t*)(xsrc + 4);
    stageW(0, 0);
    stageW(1, 1);
    *(float4_t*)(&xb[0][xw0]) = xE0;          // compiler waits xE, keeps gW flying
    *(float4_t*)(&xb[0][xw1]) = xE1;
    xO0 = *(const float4_t*)(xsrc + 32);
    xO1 = *(const float4_t*)(xsrc + 36);
    LGKM0; BARRIER;

    int cur = 0, bn1 = 1, bn2 = 2;
#pragma unroll 1
    for (int k = 0; k < 32; k += 2) {
        // ======== even step k: loads xE=x(k+2), computes buf cur, writes x(k+1)
        if (k < 30) {
            xE0 = *(const float4_t*)(xsrc + (size_t)(k + 2) * 32);
            xE1 = *(const float4_t*)(xsrc + (size_t)(k + 2) * 32 + 4);
            stageW(k + 2, bn2);
        }
        if (k < 30) { if (split) { VMCNT(12); } else { VMCNT(8); } }
        else        { if (split) { VMCNT(6);  } else { VMCNT(4); } }   // k==30
        BARRIER;
        compute(cur);
        *(float4_t*)(&xb[bn1][xw0]) = xO0;    // x(k+1), regs from prev odd step
        *(float4_t*)(&xb[bn1][xw1]) = xO1;
        LGKM0; BARRIER;
        // ======== odd step k+1: loads xO=x(k+3), computes bn1, writes x(k+2)
        int ko = k + 1;
        if (ko < 30) {
            xO0 = *(const float4_t*)(xsrc + (size_t)(ko + 2) * 32);
            xO1 = *(const float4_t*)(xsrc + (size_t)(ko + 2) * 32 + 4);
            stageW(ko + 2, cur);              // (k+3)%3 == cur
        }
        if (ko < 30)       { if (split) { VMCNT(12); } else { VMCNT(8); } }
        else if (ko == 30) { if (split) { VMCNT(6);  } else { VMCNT(4); } }
        else               { VMCNT(0); }      // ko==31
        BARRIER;
        compute(bn1);
        if (ko < 31) {
            *(float4_t*)(&xb[bn2][xw0]) = xE0;
            *(float4_t*)(&xb[bn2][xw1]) = xE1;
        }
        LGKM0; BARRIER;
        int tmp = bn2; bn2 = bn1; bn1 = cur; cur = tmp;   // rotate for k+2
    }

    // ---- epilogue: bias, split-cast, scatter into fragment-major images
    const float* bias = (grp == 0) ? bq : (grp == 1) ? bk : bv;
#pragma unroll
    for (int rf = 0; rf < 2; ++rf)
#pragma unroll
        for (int cf = 0; cf < 4; ++cf) {
            int c = wc * 64 + cf * 16 + cc;
            float bv_ = bias[c];
#pragma unroll
            for (int i = 0; i < 4; ++i) {
                int r = rowbase + wr * 32 + rf * 16 + g * 4 + i;
                float v = acc[rf][cf][i] + bv_;
                unsigned short h = f2bf(v);
                if (grp == 0) {
                    size_t o = (size_t)(r >> 4) * 2048 + (c >> 5) * 512 +
                               ((c >> 3) & 3) * 128 + (r & 15) * 8 + (c & 7);
                    qih[o] = h; qil[o] = f2bf(v - bf2f(h));
                } else if (grp == 1) {
                    size_t o = (size_t)(r >> 5) * 4096 + ((r >> 4) & 1) * 2048 +
                               (c >> 5) * 512 + ((c >> 3) & 3) * 128 +
                               (r & 15) * 8 + (c & 7);
                    kih[o] = h; kil[o] = f2bf(v - bf2f(h));
                } else {
                    size_t o = (size_t)(r >> 5) * 4096 + (c >> 4) * 512 +
                               ((r >> 3) & 3) * 128 + (c & 15) * 8 + (r & 7);
                    vit[o] = h;
                }
            }
        }
}

// ---------------------------------------------------------------------------
// K2 v5: out_partial = cos(Q K^T) V. grid (MC=4, L/64, B); 4 waves, 16 q-rows.
// Ring-3 K/V buffers, prefetch distance 2, exact vmcnt ledger.
// ---------------------------------------------------------------------------
__global__ __launch_bounds__(256, 2) void k2_attn(
        const unsigned short* __restrict__ qih, const unsigned short* __restrict__ qil,
        const unsigned short* __restrict__ kih, const unsigned short* __restrict__ kil,
        const unsigned short* __restrict__ vit, float* __restrict__ part) {
    int mc = blockIdx.x, qt = blockIdx.y, b = blockIdx.z;
    int t = threadIdx.x, lane = t & 63, wid = t >> 6;
    int cc = lane & 15, g = lane >> 4;

    __shared__ __attribute__((aligned(16))) unsigned short kbh[3][4096];
    __shared__ __attribute__((aligned(16))) unsigned short kbl[3][4096];
    __shared__ __attribute__((aligned(16))) unsigned short vbt[3][4096];
    __shared__ __attribute__((aligned(16))) unsigned short ps[4][512];

    int qrow = b * LL + qt * 64 + wid * 16;
    size_t qb = (size_t)(qrow >> 4) * 2048;
    short8_t qhf[4], qlf[4];
#pragma unroll
    for (int s = 0; s < 4; ++s) {
        size_t off = qb + s * 512 + g * 128 + cc * 8;
        qhf[s] = *(const short8_t*)(qih + off);
        qlf[s] = *(const short8_t*)(qil + off);
    }
    float4_t o[8];
#pragma unroll
    for (int cf = 0; cf < 8; ++cf) o[cf] = (float4_t){0.f, 0.f, 0.f, 0.f};

    int tbase = b * 64 + mc * 16;   // 32-row tile index base

    auto stageKV = [&](int tile, int buf) {
        const unsigned short* ks = kih + (size_t)tile * 4096;
        const unsigned short* ls = kil + (size_t)tile * 4096;
        const unsigned short* vs = vit + (size_t)tile * 4096;
        gload16(ks + t * 8, (char*)kbh[buf] + wid * 1024);
        gload16(ks + 2048 + t * 8, (char*)kbh[buf] + 4096 + wid * 1024);
        gload16(ls + t * 8, (char*)kbl[buf] + wid * 1024);
        gload16(ls + 2048 + t * 8, (char*)kbl[buf] + 4096 + wid * 1024);
        gload16(vs + t * 8, (char*)vbt[buf] + wid * 1024);
        gload16(vs + 2048 + t * 8, (char*)vbt[buf] + 4096 + wid * 1024);
    };

    stageKV(tbase + 0, 0);
    stageKV(tbase + 1, 1);

    int cur = 0, bn1 = 1, bn2 = 2;
#pragma unroll 1
    for (int mi = 0; mi < 16; ++mi) {
        if (mi < 14) stageKV(tbase + mi + 2, bn2);
        if (mi < 14)       { VMCNT(12); }
        else if (mi == 14) { VMCNT(6); }
        else               { VMCNT(0); }
        BARRIER;
        // ---- S = Q K^T (3-term split), S-tile 16q x 32m
        float4_t sa[2];
#pragma unroll
        for (int cf = 0; cf < 2; ++cf) sa[cf] = (float4_t){0.f, 0.f, 0.f, 0.f};
#pragma unroll
        for (int cf = 0; cf < 2; ++cf)
#pragma unroll
            for (int s = 0; s < 4; ++s) {
                int off = cf * 2048 + s * 512 + g * 128 + cc * 8;
                short8_t bh = *(const short8_t*)(&kbh[cur][off]);
                short8_t bl = *(const short8_t*)(&kbl[cur][off]);
                sa[cf] = MFMA(qhf[s], bh, sa[cf], 0, 0, 0);
                sa[cf] = MFMA(qhf[s], bl, sa[cf], 0, 0, 0);
                sa[cf] = MFMA(qlf[s], bh, sa[cf], 0, 0, 0);
            }
        // ---- P = cos(S) -> per-wave fragment-major LDS [m>>3][q][m&7]
#pragma unroll
        for (int cf = 0; cf < 2; ++cf)
#pragma unroll
            for (int i = 0; i < 4; ++i) {
                float rv = sa[cf][i] * INV2PI;
                rv = rv - floorf(rv);
                float cv;
                asm volatile("v_cos_f32 %0, %1" : "=v"(cv) : "v"(rv));
                int m = cf * 16 + cc, q = g * 4 + i;
                ps[wid][(m >> 3) * 128 + q * 8 + (m & 7)] = f2bf(cv);
            }
        // ---- out += P @ V  (same-wave LDS write->read; compiler lgkm-orders)
        short8_t pa = *(const short8_t*)(&ps[wid][g * 128 + cc * 8]);
#pragma unroll
        for (int cf = 0; cf < 8; ++cf) {
            short8_t vb = *(const short8_t*)(&vbt[cur][cf * 512 + g * 128 + cc * 8]);
            o[cf] = MFMA(pa, vb, o[cf], 0, 0, 0);
        }
        BARRIER;
        int tmp = cur; cur = bn1; bn1 = bn2; bn2 = tmp;   // rotate
    }
    float* pp = part + ((size_t)(mc * BB + b) * LL + qt * 64 + wid * 16) * DK;
#pragma unroll
    for (int cf = 0; cf < 8; ++cf)
#pragma unroll
        for (int i = 0; i < 4; ++i)
            pp[(g * 4 + i) * DK + cf * 16 + cc] = o[cf][i];
}

// ---------------------------------------------------------------------------
// K3: out = sum of MC partials
// ---------------------------------------------------------------------------
__global__ __launch_bounds__(256) void k3_reduce(const float4_t* __restrict__ part,
                                                 float4_t* __restrict__ out) {
    constexpr int NT4 = MTOT * DK / 4;
    int idx = blockIdx.x * 256 + threadIdx.x;
    float4_t s = part[idx];
#pragma unroll
    for (int c = 1; c < MC; ++c) s += part[idx + (size_t)c * NT4];
    out[idx] = s;
}

// ---------------------------------------------------------------------------
extern "C" void kernel_launch(void* const* d_in, const int* in_sizes, int n_in,
                              void* d_out, int out_size, void* d_ws, size_t ws_size,
                              hipStream_t stream) {
    const float* x  = (const float*)d_in[0];
    const float* Wq = (const float*)d_in[1];
    const float* bq = (const float*)d_in[2];
    const float* Wk = (const float*)d_in[3];
    const float* bk = (const float*)d_in[4];
    const float* Wv = (const float*)d_in[5];
    const float* bv = (const float*)d_in[6];

    char* ws = (char*)d_ws;
    size_t off = 0;
    auto alloc = [&](size_t bytes) -> char* {
        char* p = ws + off;
        off += (bytes + 255) & ~(size_t)255;
        return p;
    };
    unsigned short* wqh = (unsigned short*)alloc((size_t)DK * DM * 2);
    unsigned short* wql = (unsigned short*)alloc((size_t)DK * DM * 2);
    unsigned short* wkh = (unsigned short*)alloc((size_t)DK * DM * 2);
    unsigned short* wkl = (unsigned short*)alloc((size_t)DK * DM * 2);
    unsigned short* wvh = (unsigned short*)alloc((size_t)DK * DM * 2);
    unsigned short* qih = (unsigned short*)alloc((size_t)MTOT * DK * 2);
    unsigned short* qil = (unsigned short*)alloc((size_t)MTOT * DK * 2);
    unsigned short* kih = (unsigned short*)alloc((size_t)MTOT * DK * 2);
    unsigned short* kil = (unsigned short*)alloc((size_t)MTOT * DK * 2);
    unsigned short* vit = (unsigned short*)alloc((size_t)MTOT * DK * 2);
    float* part = (float*)alloc((size_t)MC * MTOT * DK * 4);

    k0_wsplit<<<dim3(32, 3), 256, 0, stream>>>(Wq, Wk, Wv, wqh, wql, wkh, wkl, wvh);
    k1_proj<<<dim3(MTOT / 64, 3), 256, 0, stream>>>(x, bq, bk, bv,
                                                    wqh, wql, wkh, wkl, wvh,
                                                    qih, qil, kih, kil, vit);
    k2_attn<<<dim3(MC, LL / 64, BB), 256, 0, stream>>>(qih, qil, kih, kil, vit, part);
    k3_reduce<<<(MTOT * DK / 4) / 256, 256, 0, stream>>>((const float4_t*)part,
                                                         (float4_t*)d_out);
}

// Round 9
// 49.452 us; speedup vs baseline: 1.6597x; 1.6597x over previous
//
#include <hip/hip_runtime.h>

typedef _Float16 half8_t __attribute__((ext_vector_type(8)));    // 8 fp16 = MFMA frag
typedef __attribute__((ext_vector_type(4))) float float4_t;      // MFMA C/D frag

#define MFMA16 __builtin_amdgcn_mfma_f32_16x16x32_f16

constexpr int BB   = 4;
constexpr int LL   = 2048;
constexpr int DM   = 1024;
constexpr int DK   = 128;
constexpr int MTOT = BB * LL;     // 8192
constexpr int MC   = 4;
constexpr float INV2PI = 0.15915494309189535f;

// Fragment-major fp16 images everywhere: a lane's MFMA fragment is one
// contiguous 16B chunk; gload_lds staging is linear (pre-permuted images).

__device__ __forceinline__ void gload16(const void* g, void* l) {
    __builtin_amdgcn_global_load_lds(
        (const __attribute__((address_space(1))) void*)g,
        (__attribute__((address_space(3))) void*)l, 16, 0, 0);
}

// ---------------------------------------------------------------------------
// K0: W [1024 k][128 n] f32 -> fragment-major W^T fp16 image.
// Per kc (64-k chunk), 8192 halfs: [cbt 8][s 8][cc 16][e 8];
// n = cbt*16+cc, k = (s>>2)*32 + (s&3)*8 + e.  grid (16 kc, 3 arr).
// ---------------------------------------------------------------------------
__global__ __launch_bounds__(256) void k0_wsplit(
        const float* __restrict__ wq, const float* __restrict__ wk,
        const float* __restrict__ wv,
        _Float16* __restrict__ wq6, _Float16* __restrict__ wk6,
        _Float16* __restrict__ wv6) {
    int kc = blockIdx.x, a = blockIdx.y;
    const float* w = (a == 0) ? wq : (a == 1) ? wk : wv;
    _Float16* dst = (a == 0) ? wq6 : (a == 1) ? wk6 : wv6;
    __shared__ float tile[64 * 132];          // [k 64][n 128] pad->132
    int t = threadIdx.x;
#pragma unroll
    for (int j = 0; j < 8; ++j) {
        int idx4 = t + j * 256;               // 2048 float4s
        int kr = idx4 >> 5, n4 = idx4 & 31;
        *(float4_t*)(&tile[kr * 132 + n4 * 4]) =
            *(const float4_t*)(w + (size_t)(kc * 64 + kr) * DK + n4 * 4);
    }
    __syncthreads();
#pragma unroll
    for (int sw = 0; sw < 4; ++sw) {
        int ch = t + sw * 256;                // 1024 chunks of 8 halfs
        int cbt = ch >> 7, s = (ch >> 4) & 7, cc = ch & 15;
        int kb = (s >> 2) * 32 + (s & 3) * 8;
        int n = cbt * 16 + cc;
        half8_t h;
#pragma unroll
        for (int e = 0; e < 8; ++e) h[e] = (_Float16)tile[(kb + e) * 132 + n];
        *(half8_t*)(dst + (size_t)kc * 8192 + ch * 8) = h;
    }
}

// ---------------------------------------------------------------------------
// K1 v8: QKV projection, fp16 single-term. BM=32, BK=64, BN=128;
// grid (256 mt, 3 grp); 4 waves, wave tile 32r x 32c. Simple 2-phase:
// stage(k+1) -> compute(k) -> one __syncthreads. LDS 50KB -> 3 blocks/CU.
// ---------------------------------------------------------------------------
__global__ __launch_bounds__(256, 3) void k1_proj(
        const float* __restrict__ x,
        const float* __restrict__ bq, const float* __restrict__ bk,
        const float* __restrict__ bv,
        const _Float16* __restrict__ wq6, const _Float16* __restrict__ wk6,
        const _Float16* __restrict__ wv6,
        _Float16* __restrict__ qim, _Float16* __restrict__ kim,
        _Float16* __restrict__ vim) {
    int mt = blockIdx.x, grp = blockIdx.y;
    int rowbase = mt * 32;
    __shared__ __attribute__((aligned(16))) _Float16 xs[2][32 * 72];  // 4.5KB ea
    __shared__ __attribute__((aligned(16))) _Float16 wsm[2][8192];    // 16KB ea

    int t = threadIdx.x, lane = t & 63, wid = t >> 6;
    int cc = lane & 15, g = lane >> 4;
    const _Float16* W6 = (grp == 0) ? wq6 : (grp == 1) ? wk6 : wv6;

    float4_t acc[2][2];
#pragma unroll
    for (int rf = 0; rf < 2; ++rf)
#pragma unroll
        for (int cf = 0; cf < 2; ++cf) acc[rf][cf] = (float4_t){0.f, 0.f, 0.f, 0.f};

    // x map: thread -> row r = t>>3 (32), 8-f32 chunk c8 = t&7 (64 k's)
    int xr = t >> 3, xc8 = t & 7;
    const float* xsrc = x + (size_t)(rowbase + xr) * DM + xc8 * 8;
    int xoff = xr * 72 + xc8 * 8;

    auto stageW = [&](int kc, int buf) {
        const _Float16* Wp = W6 + (size_t)kc * 8192;
#pragma unroll
        for (int i = 0; i < 4; ++i)
            gload16(Wp + i * 2048 + t * 8, (char*)wsm[buf] + i * 4096 + wid * 1024);
    };
    auto cvt8 = [&](float4_t f0, float4_t f1) {
        half8_t h;
#pragma unroll
        for (int e = 0; e < 4; ++e) { h[e] = (_Float16)f0[e]; h[e + 4] = (_Float16)f1[e]; }
        return h;
    };

    // prologue: x(0) + W(0) into buf 0
    {
        float4_t f0 = *(const float4_t*)(xsrc);
        float4_t f1 = *(const float4_t*)(xsrc + 4);
        stageW(0, 0);
        *(half8_t*)(xs[0] + xoff) = cvt8(f0, f1);
    }
    __syncthreads();

#pragma unroll 1
    for (int kc = 0; kc < 16; ++kc) {
        int cb = kc & 1, nb = cb ^ 1;
        bool more = (kc < 15);
        float4_t f0, f1;
        if (more) {
            f0 = *(const float4_t*)(xsrc + (size_t)(kc + 1) * 64);
            f1 = *(const float4_t*)(xsrc + (size_t)(kc + 1) * 64 + 4);
            stageW(kc + 1, nb);
        }
        // compute on cb
        half8_t a_[2][2], b_[2][2];
#pragma unroll
        for (int rf = 0; rf < 2; ++rf)
#pragma unroll
            for (int ks = 0; ks < 2; ++ks)
                a_[rf][ks] = *(const half8_t*)(xs[cb] + (rf * 16 + cc) * 72 + ks * 32 + g * 8);
#pragma unroll
        for (int cf = 0; cf < 2; ++cf)
#pragma unroll
            for (int ks = 0; ks < 2; ++ks)
                b_[cf][ks] = *(const half8_t*)(wsm[cb] + (wid * 2 + cf) * 1024 +
                                               (ks * 4 + g) * 128 + cc * 8);
#pragma unroll
        for (int cf = 0; cf < 2; ++cf)
#pragma unroll
            for (int rf = 0; rf < 2; ++rf) {
                acc[rf][cf] = MFMA16(a_[rf][0], b_[cf][0], acc[rf][cf], 0, 0, 0);
                acc[rf][cf] = MFMA16(a_[rf][1], b_[cf][1], acc[rf][cf], 0, 0, 0);
            }
        if (more) *(half8_t*)(xs[nb] + xoff) = cvt8(f0, f1);
        __syncthreads();
    }

    // epilogue: bias + scatter into fragment-major fp16 images
    const float* bias = (grp == 0) ? bq : (grp == 1) ? bk : bv;
#pragma unroll
    for (int rf = 0; rf < 2; ++rf)
#pragma unroll
        for (int cf = 0; cf < 2; ++cf) {
            int c = wid * 32 + cf * 16 + cc;
            float bv_ = bias[c];
#pragma unroll
            for (int i = 0; i < 4; ++i) {
                int r = rowbase + rf * 16 + g * 4 + i;
                float v = acc[rf][cf][i] + bv_;
                if (grp == 0) {
                    size_t o = (size_t)(r >> 4) * 2048 + (c >> 5) * 512 +
                               ((c >> 3) & 3) * 128 + (r & 15) * 8 + (c & 7);
                    qim[o] = (_Float16)v;
                } else if (grp == 1) {
                    size_t o = (size_t)(r >> 5) * 4096 + ((r >> 4) & 1) * 2048 +
                               (c >> 5) * 512 + ((c >> 3) & 3) * 128 +
                               (r & 15) * 8 + (c & 7);
                    kim[o] = (_Float16)v;
                } else {
                    size_t o = (size_t)(r >> 5) * 4096 + (c >> 4) * 512 +
                               ((r >> 3) & 3) * 128 + (c & 15) * 8 + (r & 7);
                    vim[o] = (_Float16)v;
                }
            }
        }
}

// ---------------------------------------------------------------------------
// K2 v6: out_partial = cos(Q K^T) V, fp16. grid (MC=4, L/64, B); 4 waves,
// 16 q-rows each; KVBLK=64 (2 image tiles), 8 steps, 2-phase double buffer.
// LDS 72KB -> 2 blocks/CU.
// ---------------------------------------------------------------------------
__global__ __launch_bounds__(256, 2) void k2_attn(
        const _Float16* __restrict__ qim, const _Float16* __restrict__ kim,
        const _Float16* __restrict__ vim, float* __restrict__ part) {
    int mc = blockIdx.x, qt = blockIdx.y, b = blockIdx.z;
    int t = threadIdx.x, lane = t & 63, wid = t >> 6;
    int cc = lane & 15, g = lane >> 4;

    __shared__ __attribute__((aligned(16))) _Float16 kb[2][8192];   // 16KB ea
    __shared__ __attribute__((aligned(16))) _Float16 vb[2][8192];   // 16KB ea
    __shared__ __attribute__((aligned(16))) _Float16 ps[4][1024];   // per-wave P

    int qrow = b * LL + qt * 64 + wid * 16;
    const _Float16* qb_ = qim + (size_t)(qrow >> 4) * 2048;
    half8_t qf[4];
#pragma unroll
    for (int s = 0; s < 4; ++s)
        qf[s] = *(const half8_t*)(qb_ + s * 512 + g * 128 + cc * 8);

    float4_t o[8];
#pragma unroll
    for (int cf = 0; cf < 8; ++cf) o[cf] = (float4_t){0.f, 0.f, 0.f, 0.f};

    int tbase = b * 64 + mc * 16;   // 32-row tile index base

    auto stageKV = [&](int mi, int buf) {
        const _Float16* ks = kim + (size_t)(tbase + mi * 2) * 4096;
        const _Float16* vs = vim + (size_t)(tbase + mi * 2) * 4096;
#pragma unroll
        for (int i = 0; i < 4; ++i) {
            gload16(ks + i * 2048 + t * 8, (char*)kb[buf] + i * 4096 + wid * 1024);
            gload16(vs + i * 2048 + t * 8, (char*)vb[buf] + i * 4096 + wid * 1024);
        }
    };

    stageKV(0, 0);
    __syncthreads();

#pragma unroll 1
    for (int mi = 0; mi < 8; ++mi) {
        int cb = mi & 1, nb = cb ^ 1;
        if (mi < 7) stageKV(mi + 1, nb);
        // ---- S = Q K^T, S-tile 16q x 64m
        float4_t sa[4];
#pragma unroll
        for (int cf = 0; cf < 4; ++cf) sa[cf] = (float4_t){0.f, 0.f, 0.f, 0.f};
#pragma unroll
        for (int cf = 0; cf < 4; ++cf)
#pragma unroll
            for (int s = 0; s < 4; ++s) {
                half8_t bh = *(const half8_t*)(kb[cb] + cf * 2048 + s * 512 +
                                               g * 128 + cc * 8);
                sa[cf] = MFMA16(qf[s], bh, sa[cf], 0, 0, 0);
            }
        // ---- P = cos(S) -> per-wave fragment-major LDS [m>>3][q][m&7]
#pragma unroll
        for (int cf = 0; cf < 4; ++cf)
#pragma unroll
            for (int i = 0; i < 4; ++i) {
                float rv = sa[cf][i] * INV2PI;
                rv = rv - floorf(rv);
                float cv;
                asm volatile("v_cos_f32 %0, %1" : "=v"(cv) : "v"(rv));
                int m = cf * 16 + cc, q = g * 4 + i;
                ps[wid][(m >> 3) * 128 + q * 8 + (m & 7)] = (_Float16)cv;
            }
        // ---- out += P @ V
#pragma unroll
        for (int ksv = 0; ksv < 2; ++ksv) {
            half8_t pa = *(const half8_t*)(&ps[wid][(ksv * 4 + g) * 128 + cc * 8]);
#pragma unroll
            for (int cf = 0; cf < 8; ++cf) {
                half8_t vbf = *(const half8_t*)(vb[cb] + ksv * 4096 + cf * 512 +
                                                g * 128 + cc * 8);
                o[cf] = MFMA16(pa, vbf, o[cf], 0, 0, 0);
            }
        }
        __syncthreads();
    }
    float* pp = part + ((size_t)(mc * BB + b) * LL + qt * 64 + wid * 16) * DK;
#pragma unroll
    for (int cf = 0; cf < 8; ++cf)
#pragma unroll
        for (int i = 0; i < 4; ++i)
            pp[(g * 4 + i) * DK + cf * 16 + cc] = o[cf][i];
}

// ---------------------------------------------------------------------------
// K3: out = sum of MC partials
// ---------------------------------------------------------------------------
__global__ __launch_bounds__(256) void k3_reduce(const float4_t* __restrict__ part,
                                                 float4_t* __restrict__ out) {
    constexpr int NT4 = MTOT * DK / 4;
    int idx = blockIdx.x * 256 + threadIdx.x;
    float4_t s = part[idx];
#pragma unroll
    for (int c = 1; c < MC; ++c) s += part[idx + (size_t)c * NT4];
    out[idx] = s;
}

// ---------------------------------------------------------------------------
extern "C" void kernel_launch(void* const* d_in, const int* in_sizes, int n_in,
                              void* d_out, int out_size, void* d_ws, size_t ws_size,
                              hipStream_t stream) {
    const float* x  = (const float*)d_in[0];
    const float* Wq = (const float*)d_in[1];
    const float* bq = (const float*)d_in[2];
    const float* Wk = (const float*)d_in[3];
    const float* bk = (const float*)d_in[4];
    const float* Wv = (const float*)d_in[5];
    const float* bv = (const float*)d_in[6];

    char* ws = (char*)d_ws;
    size_t off = 0;
    auto alloc = [&](size_t bytes) -> char* {
        char* p = ws + off;
        off += (bytes + 255) & ~(size_t)255;
        return p;
    };
    _Float16* wq6 = (_Float16*)alloc((size_t)DK * DM * 2);
    _Float16* wk6 = (_Float16*)alloc((size_t)DK * DM * 2);
    _Float16* wv6 = (_Float16*)alloc((size_t)DK * DM * 2);
    _Float16* qim = (_Float16*)alloc((size_t)MTOT * DK * 2);
    _Float16* kim = (_Float16*)alloc((size_t)MTOT * DK * 2);
    _Float16* vim = (_Float16*)alloc((size_t)MTOT * DK * 2);
    float* part = (float*)alloc((size_t)MC * MTOT * DK * 4);

    k0_wsplit<<<dim3(16, 3), 256, 0, stream>>>(Wq, Wk, Wv, wq6, wk6, wv6);
    k1_proj<<<dim3(MTOT / 32, 3), 256, 0, stream>>>(x, bq, bk, bv,
                                                    wq6, wk6, wv6, qim, kim, vim);
    k2_attn<<<dim3(MC, LL / 64, BB), 256, 0, stream>>>(qim, kim, vim, part);
    k3_reduce<<<(MTOT * DK / 4) / 256, 256, 0, stream>>>((const float4_t*)part,
                                                         (float4_t*)d_out);
}